// Round 3
// baseline (157.813 us; speedup 1.0000x reference)
//
#include <hip/hip_runtime.h>

#define N 2048
#define T 32
#define D 128
#define BT 32
#define MT (N / BT)                // 64 row-blocks
#define NTILES (MT * (MT + 1) / 2) // 2080 upper-triangular tiles
#define STR 36  // padded row stride: row starts at bank 4r%32 -> b128 reads over 8 rows are conflict-free

// s_waitcnt lgkmcnt(0) ONLY (vmcnt=63, expcnt=7) — gfx9 encoding 0xc07f.
// Single-wave workgroups: lanes are lockstep, no s_barrier needed; this keeps
// global prefetch loads in flight across LDS sync points (unlike __syncthreads,
// which drains vmcnt(0)).
#define LGKM0() __builtin_amdgcn_s_waitcnt(0xc07f)

// ---------------------------------------------------------------------------
// Fused kernel: one 32x32 pair tile per 64-thread (1-wave) block.
// Raw-dot accumulation + epilogue normalization (row norms computed in-flight
// from the staged X values), register-prefetched K stages, hinge via
// max(|d|,s) - s identity (3 VALU ops/unit instead of 4).
// ---------------------------------------------------------------------------
__global__ __launch_bounds__(64, 2) void pair_kernel(
    const float* __restrict__ pred,     // [N][T]
    const float* __restrict__ X,        // [N][D]
    const float* __restrict__ scale_p,  // [1]
    double* __restrict__ partials) {    // [NTILES]
  __shared__ float As[BT * STR], Bs[BT * STR];   // X feature chunks (raw)
  __shared__ float Pa[BT * STR], Pb[BT * STR];   // prediction rows
  __shared__ float nrmA[BT], nrmB[BT];           // 1/||row||

  // linear tile id -> (a,b), a<=b
  const int t = blockIdx.x;
  int a = (int)((2 * MT + 1 -
                 sqrtf((float)((2 * MT + 1) * (2 * MT + 1) - 8 * t))) * 0.5f);
  while (a > 0 && t < a * MT - a * (a - 1) / 2) --a;
  while (t >= (a + 1) * MT - (a + 1) * a / 2) ++a;
  const int b = a + (t - (a * MT - a * (a - 1) / 2));

  const int tid  = threadIdx.x;
  const int srow = tid >> 1;            // staging row 0..31
  const int co   = (tid & 1) << 4;      // staging col half: 0 or 16
  const int aRow0 = a * BT, bRow0 = b * BT;
  const float scale = scale_p[0];

  // ---- prefetch predictions (held in registers through the dot phase)
  const float* par = pred + (size_t)(aRow0 + srow) * T + co;
  const float* pbr = pred + (size_t)(bRow0 + srow) * T + co;
  float4 pra[4], prb[4];
#pragma unroll
  for (int j = 0; j < 4; ++j) {
    pra[j] = *(const float4*)(par + 4 * j);
    prb[j] = *(const float4*)(pbr + 4 * j);
  }

  // ---- prefetch X stage 0
  const float* xar = X + (size_t)(aRow0 + srow) * D + co;
  const float* xbr = X + (size_t)(bRow0 + srow) * D + co;
  float4 xa[4], xb[4];
#pragma unroll
  for (int j = 0; j < 4; ++j) {
    xa[j] = *(const float4*)(xar + 4 * j);
    xb[j] = *(const float4*)(xbr + 4 * j);
  }

  const int tx = tid & 7, ty = tid >> 3;
  float dot[4][4];
#pragma unroll
  for (int i = 0; i < 4; ++i)
#pragma unroll
    for (int l = 0; l < 4; ++l) dot[i][l] = 0.0f;
  float ssA = 0.0f, ssB = 0.0f;

  // ---- K loop: 4 stages of 32 features, register-prefetched
  for (int dc = 0; dc < 4; ++dc) {
#pragma unroll
    for (int j = 0; j < 4; ++j) {
      *(float4*)(&As[srow * STR + co + 4 * j]) = xa[j];
      *(float4*)(&Bs[srow * STR + co + 4 * j]) = xb[j];
      ssA += xa[j].x * xa[j].x + xa[j].y * xa[j].y +
             xa[j].z * xa[j].z + xa[j].w * xa[j].w;
      ssB += xb[j].x * xb[j].x + xb[j].y * xb[j].y +
             xb[j].z * xb[j].z + xb[j].w * xb[j].w;
    }
    if (dc < 3) {  // issue next stage's global loads; they fly over the FMAs
#pragma unroll
      for (int j = 0; j < 4; ++j) {
        xa[j] = *(const float4*)(xar + (dc + 1) * 32 + 4 * j);
        xb[j] = *(const float4*)(xbr + (dc + 1) * 32 + 4 * j);
      }
    }
    LGKM0();  // LDS writes visible (single wave: no barrier needed)
#pragma unroll
    for (int d4 = 0; d4 < 8; ++d4) {
      float4 a4[4], b4[4];
#pragma unroll
      for (int i = 0; i < 4; ++i) {
        a4[i] = *(const float4*)(&As[(ty + 8 * i) * STR + d4 * 4]);
        b4[i] = *(const float4*)(&Bs[(tx + 8 * i) * STR + d4 * 4]);
      }
#pragma unroll
      for (int i = 0; i < 4; ++i)
#pragma unroll
        for (int l = 0; l < 4; ++l)
          dot[i][l] += a4[i].x * b4[l].x + a4[i].y * b4[l].y +
                       a4[i].z * b4[l].z + a4[i].w * b4[l].w;
    }
    LGKM0();  // reads done before next stage overwrites (in-order DS per wave)
  }

  // ---- finish norms (thread covers 64 cols; partner tid^1 the other 64)
  ssA += __shfl_xor(ssA, 1, 64);
  ssB += __shfl_xor(ssB, 1, 64);
  if ((tid & 1) == 0) {
    nrmA[srow] = rsqrtf(ssA);
    nrmB[srow] = rsqrtf(ssB);
  }
  // ---- stage predictions from registers
#pragma unroll
  for (int j = 0; j < 4; ++j) {
    *(float4*)(&Pa[srow * STR + co + 4 * j]) = pra[j];
    *(float4*)(&Pb[srow * STR + co + 4 * j]) = prb[j];
  }
  LGKM0();

  // ---- epilogue: sd = scale*(1 - dot*na*nb); reuse dot[][] for sd
  float na[4], nb[4];
#pragma unroll
  for (int i = 0; i < 4; ++i) {
    na[i] = nrmA[ty + 8 * i];
    nb[i] = nrmB[tx + 8 * i];
  }
  float ps[4][4];
#pragma unroll
  for (int i = 0; i < 4; ++i)
#pragma unroll
    for (int l = 0; l < 4; ++l) {
      dot[i][l] = scale * (1.0f - dot[i][l] * na[i] * nb[l]);
      ps[i][l]  = 0.0f;
    }

  // ---- hinge: sum_t max(s,|dp|), correct by -32*s at the end
#pragma unroll
  for (int t4 = 0; t4 < 8; ++t4) {
    float4 qa[4], qb[4];
#pragma unroll
    for (int i = 0; i < 4; ++i) {
      qa[i] = *(const float4*)(&Pa[(ty + 8 * i) * STR + t4 * 4]);
      qb[i] = *(const float4*)(&Pb[(tx + 8 * i) * STR + t4 * 4]);
    }
#pragma unroll
    for (int i = 0; i < 4; ++i)
#pragma unroll
      for (int l = 0; l < 4; ++l) {
        float s = dot[i][l];
        float d0 = qa[i].x - qb[l].x;
        float d1 = qa[i].y - qb[l].y;
        float d2 = qa[i].z - qb[l].z;
        float d3 = qa[i].w - qb[l].w;
        ps[i][l] += fmaxf(fmaxf(d0, -d0), s) + fmaxf(fmaxf(d1, -d1), s) +
                    fmaxf(fmaxf(d2, -d2), s) + fmaxf(fmaxf(d3, -d3), s);
      }
  }

  // ---- triangular mask + hinge correction + reduction
  float tsum = 0.0f;
  const bool offdiag = (b > a);
#pragma unroll
  for (int i = 0; i < 4; ++i)
#pragma unroll
    for (int l = 0; l < 4; ++l) {
      int jy = ty + 8 * i, kx = tx + 8 * l;
      bool valid = offdiag || (kx > jy);
      tsum += valid ? (ps[i][l] - 32.0f * dot[i][l]) : 0.0f;
    }

  double dsum = (double)tsum;
#pragma unroll
  for (int off = 32; off > 0; off >>= 1) dsum += __shfl_down(dsum, off, 64);
  if (tid == 0) partials[blockIdx.x] = dsum;
}

// ---------------------------------------------------------------------------
// Finalize: sum 2080 partials, scale, clamp.
// ---------------------------------------------------------------------------
__global__ __launch_bounds__(256) void finalize_kernel(
    const double* __restrict__ partials, const float* __restrict__ target,
    float* __restrict__ out) {
  __shared__ double red[4];
  double s = 0.0;
  for (int i = threadIdx.x; i < NTILES; i += 256) s += partials[i];
#pragma unroll
  for (int off = 32; off > 0; off >>= 1) s += __shfl_down(s, off, 64);
  int wave = threadIdx.x >> 6, lane = threadIdx.x & 63;
  if (lane == 0) red[wave] = s;
  __syncthreads();
  if (threadIdx.x == 0) {
    double tot = red[0] + red[1] + red[2] + red[3];
    double mf  = 2.0 * tot / ((double)N * (double)(N - 1) * (double)T);
    double r   = mf - (double)target[0];
    out[0] = (float)(r > 0.0 ? r : 0.0);
  }
}

extern "C" void kernel_launch(void* const* d_in, const int* in_sizes, int n_in,
                              void* d_out, int out_size, void* d_ws, size_t ws_size,
                              hipStream_t stream) {
  const float* target = (const float*)d_in[0];
  const float* pred   = (const float*)d_in[1];
  const float* X      = (const float*)d_in[2];
  // d_in[3] = ntimes (==32, hardcoded); d_in[4] = scale
  const float* scale  = (const float*)d_in[4];

  double* partials = (double*)d_ws;  // NTILES doubles, all written every call

  pair_kernel<<<dim3(NTILES), dim3(64), 0, stream>>>(pred, X, scale, partials);
  finalize_kernel<<<dim3(1), dim3(256), 0, stream>>>(partials, target,
                                                     (float*)d_out);
}

// Round 4
// 97.505 us; speedup vs baseline: 1.6185x; 1.6185x over previous
//
#include <hip/hip_runtime.h>

#define N 2048
#define T 32
#define D 128
#define BT 32
#define MT (N / BT)                // 64 row-blocks
#define NTILES (MT * (MT + 1) / 2) // 2080 upper-triangular tiles
#define STR 36  // padded row stride (floats): row r starts at bank 4r%32

// s_waitcnt lgkmcnt(0) only (vmcnt=63, expcnt=7) — gfx9 encoding 0xc07f.
// Single-wave workgroups are lockstep: no s_barrier, and global loads in
// flight are never drained (unlike __syncthreads' vmcnt(0)).
#define LGKM0() __builtin_amdgcn_s_waitcnt(0xc07f)

// ---------------------------------------------------------------------------
// One 32x32 pair tile per 64-thread (single-wave) block. LEAN: no register
// prefetch across phases (R3's prefetch scheme spilled ~1.4 KB/thread —
// 192 MB scratch traffic). Latency hiding comes from ~16 co-resident
// single-wave blocks per CU (LDS = 9.4 KB/block).
// LDS reuse: SA/SB hold X chunks during the dot phase, then predictions
// during the hinge phase (DS ops are in-order per wave, so the pred writes
// cannot pass the final dot reads).
// ---------------------------------------------------------------------------
__global__ __launch_bounds__(64) void pair_kernel(
    const float* __restrict__ pred,     // [N][T]
    const float* __restrict__ X,        // [N][D]
    const float* __restrict__ scale_p,  // [1]
    double* __restrict__ partials) {    // [NTILES]
  __shared__ float SA[BT * STR], SB[BT * STR];
  __shared__ float nrmA[BT], nrmB[BT];

  // linear tile id -> (a,b), a<=b
  const int t = blockIdx.x;
  int a = (int)((2 * MT + 1 -
                 sqrtf((float)((2 * MT + 1) * (2 * MT + 1) - 8 * t))) * 0.5f);
  while (a > 0 && t < a * MT - a * (a - 1) / 2) --a;
  while (t >= (a + 1) * MT - (a + 1) * a / 2) ++a;
  const int b = a + (t - (a * MT - a * (a - 1) / 2));

  const int tid  = threadIdx.x;
  const int srow = tid >> 1;            // staging row 0..31
  const int co   = (tid & 1) << 4;      // staging col half: 0 or 16 (floats)
  const int aRow0 = a * BT, bRow0 = b * BT;
  const float scale = scale_p[0];

  const float* xar = X + (size_t)(aRow0 + srow) * D + co;
  const float* xbr = X + (size_t)(bRow0 + srow) * D + co;

  const int tx = tid & 7, ty = tid >> 3;
  float dot[4][4];
#pragma unroll
  for (int i = 0; i < 4; ++i)
#pragma unroll
    for (int l = 0; l < 4; ++l) dot[i][l] = 0.0f;
  float ssA = 0.0f, ssB = 0.0f;

  // ---- dot phase: 4 stages of 32 features; per-stage temporaries only
  for (int dc = 0; dc < 4; ++dc) {
#pragma unroll
    for (int j = 0; j < 4; ++j) {
      float4 va = *(const float4*)(xar + dc * 32 + 4 * j);
      float4 vb = *(const float4*)(xbr + dc * 32 + 4 * j);
      ssA += va.x * va.x + va.y * va.y + va.z * va.z + va.w * va.w;
      ssB += vb.x * vb.x + vb.y * vb.y + vb.z * vb.z + vb.w * vb.w;
      *(float4*)(&SA[srow * STR + co + 4 * j]) = va;
      *(float4*)(&SB[srow * STR + co + 4 * j]) = vb;
    }
    LGKM0();  // LDS writes visible (single wave: no barrier needed)
#pragma unroll
    for (int d4 = 0; d4 < 8; ++d4) {
      float4 a4[4], b4[4];
#pragma unroll
      for (int i = 0; i < 4; ++i) {
        a4[i] = *(const float4*)(&SA[(ty + 8 * i) * STR + d4 * 4]);
        b4[i] = *(const float4*)(&SB[(tx + 8 * i) * STR + d4 * 4]);
      }
#pragma unroll
      for (int i = 0; i < 4; ++i)
#pragma unroll
        for (int l = 0; l < 4; ++l)
          dot[i][l] += a4[i].x * b4[l].x + a4[i].y * b4[l].y +
                       a4[i].z * b4[l].z + a4[i].w * b4[l].w;
    }
    // next stage's ds_writes are in-order after this stage's ds_reads: no wait
  }

  // ---- norms (thread + partner tid^1 cover the 128 features of srow)
  ssA += __shfl_xor(ssA, 1, 64);
  ssB += __shfl_xor(ssB, 1, 64);
  if ((tid & 1) == 0) {
    nrmA[srow] = rsqrtf(ssA);
    nrmB[srow] = rsqrtf(ssB);
  }

  // ---- stage predictions into SA/SB (reuse; writes ordered after dot reads)
  {
    const float* par = pred + (size_t)(aRow0 + srow) * T + co;
    const float* pbr = pred + (size_t)(bRow0 + srow) * T + co;
#pragma unroll
    for (int j = 0; j < 4; ++j) {
      *(float4*)(&SA[srow * STR + co + 4 * j]) = *(const float4*)(par + 4 * j);
      *(float4*)(&SB[srow * STR + co + 4 * j]) = *(const float4*)(pbr + 4 * j);
    }
  }
  LGKM0();

  // ---- epilogue: sd = scale*(1 - dot*na*nb); reuse dot[][] for sd
  float na[4], nb[4];
#pragma unroll
  for (int i = 0; i < 4; ++i) {
    na[i] = nrmA[ty + 8 * i];
    nb[i] = nrmB[tx + 8 * i];
  }
  float ps[4][4];
#pragma unroll
  for (int i = 0; i < 4; ++i)
#pragma unroll
    for (int l = 0; l < 4; ++l) {
      dot[i][l] = scale * (1.0f - dot[i][l] * na[i] * nb[l]);
      ps[i][l]  = 0.0f;
    }

  // ---- hinge: sum_t max(|dp|, s), corrected by -32*s in the mask pass
#pragma unroll
  for (int t4 = 0; t4 < 8; ++t4) {
    float4 qa[4], qb[4];
#pragma unroll
    for (int i = 0; i < 4; ++i) {
      qa[i] = *(const float4*)(&SA[(ty + 8 * i) * STR + t4 * 4]);
      qb[i] = *(const float4*)(&SB[(tx + 8 * i) * STR + t4 * 4]);
    }
#pragma unroll
    for (int i = 0; i < 4; ++i)
#pragma unroll
      for (int l = 0; l < 4; ++l) {
        float s = dot[i][l];
        ps[i][l] += fmaxf(fabsf(qa[i].x - qb[l].x), s) +
                    fmaxf(fabsf(qa[i].y - qb[l].y), s) +
                    fmaxf(fabsf(qa[i].z - qb[l].z), s) +
                    fmaxf(fabsf(qa[i].w - qb[l].w), s);
      }
  }

  // ---- triangular mask + hinge correction + wave reduction
  float tsum = 0.0f;
  const bool offdiag = (b > a);
#pragma unroll
  for (int i = 0; i < 4; ++i)
#pragma unroll
    for (int l = 0; l < 4; ++l) {
      int jy = ty + 8 * i, kx = tx + 8 * l;
      bool valid = offdiag || (kx > jy);
      tsum += valid ? (ps[i][l] - 32.0f * dot[i][l]) : 0.0f;
    }

  double dsum = (double)tsum;
#pragma unroll
  for (int off = 32; off > 0; off >>= 1) dsum += __shfl_down(dsum, off, 64);
  if (tid == 0) partials[blockIdx.x] = dsum;
}

// ---------------------------------------------------------------------------
// Finalize: sum 2080 partials, scale, clamp.
// ---------------------------------------------------------------------------
__global__ __launch_bounds__(256) void finalize_kernel(
    const double* __restrict__ partials, const float* __restrict__ target,
    float* __restrict__ out) {
  __shared__ double red[4];
  double s = 0.0;
  for (int i = threadIdx.x; i < NTILES; i += 256) s += partials[i];
#pragma unroll
  for (int off = 32; off > 0; off >>= 1) s += __shfl_down(s, off, 64);
  int wave = threadIdx.x >> 6, lane = threadIdx.x & 63;
  if (lane == 0) red[wave] = s;
  __syncthreads();
  if (threadIdx.x == 0) {
    double tot = red[0] + red[1] + red[2] + red[3];
    double mf  = 2.0 * tot / ((double)N * (double)(N - 1) * (double)T);
    double r   = mf - (double)target[0];
    out[0] = (float)(r > 0.0 ? r : 0.0);
  }
}

extern "C" void kernel_launch(void* const* d_in, const int* in_sizes, int n_in,
                              void* d_out, int out_size, void* d_ws, size_t ws_size,
                              hipStream_t stream) {
  const float* target = (const float*)d_in[0];
  const float* pred   = (const float*)d_in[1];
  const float* X      = (const float*)d_in[2];
  // d_in[3] = ntimes (==32, hardcoded); d_in[4] = scale
  const float* scale  = (const float*)d_in[4];

  double* partials = (double*)d_ws;  // NTILES doubles, all written every call

  pair_kernel<<<dim3(NTILES), dim3(64), 0, stream>>>(pred, X, scale, partials);
  finalize_kernel<<<dim3(1), dim3(256), 0, stream>>>(partials, target,
                                                     (float*)d_out);
}

// Round 5
// 88.091 us; speedup vs baseline: 1.7915x; 1.1069x over previous
//
#include <hip/hip_runtime.h>

#define N 2048
#define T 32
#define D 128
#define BT 32
#define MT (N / BT)                // 64 row-blocks
#define NTILES (MT * (MT + 1) / 2) // 2080 upper-triangular tiles
#define STR 36                     // padded LDS row stride (floats)

typedef float floatx4 __attribute__((ext_vector_type(4)));
typedef short bf16x8 __attribute__((ext_vector_type(8)));

// s_waitcnt lgkmcnt(0) only — gfx9 encoding 0xc07f (single-wave WG: no barrier).
#define LGKM0() __builtin_amdgcn_s_waitcnt(0xc07f)

// Split fp32 -> truncated-bf16 (h) + truncated-bf16 of the exact remainder (l).
// x = h + l + eps, |eps| <= 2^-17|x|; Gram via h*h + h*l + l*h drops only
// l*l (<= 2^-16 rel) — output error ~4e-8 vs 3.7e-6 threshold (active hinge
// fraction ~0.4%).
__device__ __forceinline__ void split8(float4 a, float4 b, bf16x8& h, bf16x8& l) {
  float v[8] = {a.x, a.y, a.z, a.w, b.x, b.y, b.z, b.w};
#pragma unroll
  for (int i = 0; i < 8; ++i) {
    unsigned u = __float_as_uint(v[i]);
    h[i] = (short)(u >> 16);                       // truncate to bf16
    float lo = v[i] - __uint_as_float(u & 0xffff0000u);  // exact
    l[i] = (short)(__float_as_uint(lo) >> 16);
  }
}

__device__ __forceinline__ float sumsq8(float4 a, float4 b) {
  return a.x * a.x + a.y * a.y + a.z * a.z + a.w * a.w +
         b.x * b.x + b.y * b.y + b.z * b.z + b.w * b.w;
}

// ---------------------------------------------------------------------------
// One 32x32 pair tile per 64-thread (single-wave) block.
// Dot phase: split-bf16 MFMA (4 subtiles of 16x16, K=128 in 4 steps of 32,
// 3 mfma per subtile-step = 48 mfma). Fragments loaded straight from global
// (X is 1 MB, L2-resident) in the native mfma layout: lane = m + 16*quad,
// element j -> A[m][k = ks*32 + quad*8 + j]. No LDS in the dot phase.
// Hinge phase: predictions staged in LDS; identity max(0,|d|-s) = max(|d|,s)-s.
// ---------------------------------------------------------------------------
__global__ __launch_bounds__(64) void pair_kernel(
    const float* __restrict__ pred,     // [N][T]
    const float* __restrict__ X,        // [N][D]
    const float* __restrict__ scale_p,  // [1]
    double* __restrict__ partials) {    // [NTILES]
  __shared__ float Pa[BT * STR], Pb[BT * STR];
  __shared__ float nrmA[BT], nrmB[BT];

  // linear tile id -> (a,b), a<=b
  const int t = blockIdx.x;
  int a = (int)((2 * MT + 1 -
                 sqrtf((float)((2 * MT + 1) * (2 * MT + 1) - 8 * t))) * 0.5f);
  while (a > 0 && t < a * MT - a * (a - 1) / 2) --a;
  while (t >= (a + 1) * MT - (a + 1) * a / 2) ++a;
  const int b = a + (t - (a * MT - a * (a - 1) / 2));

  const int tid  = threadIdx.x;
  const int m    = tid & 15;            // mfma row/col-in-subtile
  const int quad = tid >> 4;            // mfma k-quad / C-row group
  const int aRow0 = a * BT, bRow0 = b * BT;
  const float scale = scale_p[0];

  // ---- stage predictions into LDS (global loads fly over the dot phase;
  //      DS writes are wave-in-order, complete before hinge DS reads)
  {
    const int srow = tid >> 1, co = (tid & 1) << 4;
    const float* par = pred + (size_t)(aRow0 + srow) * T + co;
    const float* pbr = pred + (size_t)(bRow0 + srow) * T + co;
#pragma unroll
    for (int j = 0; j < 4; ++j) {
      *(float4*)(&Pa[srow * STR + co + 4 * j]) = *(const float4*)(par + 4 * j);
      *(float4*)(&Pb[srow * STR + co + 4 * j]) = *(const float4*)(pbr + 4 * j);
    }
  }

  // ---- dot phase: raw Gram G[j][k] = X_a[j]·X_b[k] via split-bf16 MFMA
  floatx4 acc[2][2];
#pragma unroll
  for (int I = 0; I < 2; ++I)
#pragma unroll
    for (int J = 0; J < 2; ++J) acc[I][J] = (floatx4){0.f, 0.f, 0.f, 0.f};
  float ssA[2] = {0.f, 0.f}, ssB[2] = {0.f, 0.f};

  const float* xa0 = X + (size_t)(aRow0 + m) * D + quad * 8;
  const float* xb0 = X + (size_t)(bRow0 + m) * D + quad * 8;

#pragma unroll
  for (int ks = 0; ks < 4; ++ks) {
    bf16x8 hA[2], lA[2], hB[2], lB[2];
#pragma unroll
    for (int I = 0; I < 2; ++I) {
      float4 u0 = *(const float4*)(xa0 + (size_t)I * 16 * D + ks * 32);
      float4 u1 = *(const float4*)(xa0 + (size_t)I * 16 * D + ks * 32 + 4);
      ssA[I] += sumsq8(u0, u1);
      split8(u0, u1, hA[I], lA[I]);
      float4 w0 = *(const float4*)(xb0 + (size_t)I * 16 * D + ks * 32);
      float4 w1 = *(const float4*)(xb0 + (size_t)I * 16 * D + ks * 32 + 4);
      ssB[I] += sumsq8(w0, w1);
      split8(w0, w1, hB[I], lB[I]);
    }
#pragma unroll
    for (int I = 0; I < 2; ++I)
#pragma unroll
      for (int J = 0; J < 2; ++J) {
        acc[I][J] = __builtin_amdgcn_mfma_f32_16x16x32_bf16(hA[I], hB[J],
                                                            acc[I][J], 0, 0, 0);
        acc[I][J] = __builtin_amdgcn_mfma_f32_16x16x32_bf16(hA[I], lB[J],
                                                            acc[I][J], 0, 0, 0);
        acc[I][J] = __builtin_amdgcn_mfma_f32_16x16x32_bf16(lA[I], hB[J],
                                                            acc[I][J], 0, 0, 0);
      }
  }

  // ---- norms: lane holds row-m partial over its quad's k columns;
  //      reduce across the 4 quads (lanes m, m+16, m+32, m+48)
#pragma unroll
  for (int I = 0; I < 2; ++I) {
    ssA[I] += __shfl_xor(ssA[I], 16, 64);
    ssA[I] += __shfl_xor(ssA[I], 32, 64);
    ssB[I] += __shfl_xor(ssB[I], 16, 64);
    ssB[I] += __shfl_xor(ssB[I], 32, 64);
  }
  if (quad == 0) {
#pragma unroll
    for (int I = 0; I < 2; ++I) {
      nrmA[16 * I + m] = rsqrtf(ssA[I]);
      nrmB[16 * I + m] = rsqrtf(ssB[I]);
    }
  }
  LGKM0();  // nrm + pred writes visible (single wave, DS in-order)

  // ---- epilogue: sd = scale*(1 - G*na*nb) in the mfma C-layout
  //      (thread owns rows quad*4+r of subtile I, col m of subtile J)
  float na[2][4], nb[2];
#pragma unroll
  for (int I = 0; I < 2; ++I) {
#pragma unroll
    for (int r = 0; r < 4; ++r) na[I][r] = nrmA[16 * I + quad * 4 + r];
    nb[I] = nrmB[16 * I + m];
  }
  float sd[2][2][4], ps[2][2][4];
#pragma unroll
  for (int I = 0; I < 2; ++I)
#pragma unroll
    for (int J = 0; J < 2; ++J)
#pragma unroll
      for (int r = 0; r < 4; ++r) {
        sd[I][J][r] = scale * (1.0f - acc[I][J][r] * na[I][r] * nb[J]);
        ps[I][J][r] = 0.0f;
      }

  // ---- hinge: sum_t max(|dp|, s); corrected by -32*s in the mask pass.
  //      qa reads are 16-lane broadcasts (row indep. of m); qb rows stride
  //      STR=36 -> 2-way bank aliasing only (free per m136).
#pragma unroll
  for (int t4 = 0; t4 < 8; ++t4) {
    float4 qb[2];
    qb[0] = *(const float4*)(&Pb[m * STR + t4 * 4]);
    qb[1] = *(const float4*)(&Pb[(16 + m) * STR + t4 * 4]);
#pragma unroll
    for (int I = 0; I < 2; ++I)
#pragma unroll
      for (int r = 0; r < 4; ++r) {
        float4 qa = *(const float4*)(&Pa[(16 * I + quad * 4 + r) * STR + t4 * 4]);
#pragma unroll
        for (int J = 0; J < 2; ++J) {
          float s = sd[I][J][r];
          ps[I][J][r] += fmaxf(fabsf(qa.x - qb[J].x), s) +
                         fmaxf(fabsf(qa.y - qb[J].y), s) +
                         fmaxf(fabsf(qa.z - qb[J].z), s) +
                         fmaxf(fabsf(qa.w - qb[J].w), s);
        }
      }
  }

  // ---- triangular mask + hinge correction + wave reduction
  float tsum = 0.0f;
#pragma unroll
  for (int I = 0; I < 2; ++I)
#pragma unroll
    for (int J = 0; J < 2; ++J)
#pragma unroll
      for (int r = 0; r < 4; ++r) {
        int j = aRow0 + 16 * I + quad * 4 + r;
        int k = bRow0 + 16 * J + m;
        tsum += (k > j) ? (ps[I][J][r] - 32.0f * sd[I][J][r]) : 0.0f;
      }

  double dsum = (double)tsum;
#pragma unroll
  for (int off = 32; off > 0; off >>= 1) dsum += __shfl_down(dsum, off, 64);
  if (tid == 0) partials[blockIdx.x] = dsum;
}

// ---------------------------------------------------------------------------
// Finalize: sum 2080 partials, scale, clamp.
// ---------------------------------------------------------------------------
__global__ __launch_bounds__(256) void finalize_kernel(
    const double* __restrict__ partials, const float* __restrict__ target,
    float* __restrict__ out) {
  __shared__ double red[4];
  double s = 0.0;
  for (int i = threadIdx.x; i < NTILES; i += 256) s += partials[i];
#pragma unroll
  for (int off = 32; off > 0; off >>= 1) s += __shfl_down(s, off, 64);
  int wave = threadIdx.x >> 6, lane = threadIdx.x & 63;
  if (lane == 0) red[wave] = s;
  __syncthreads();
  if (threadIdx.x == 0) {
    double tot = red[0] + red[1] + red[2] + red[3];
    double mf  = 2.0 * tot / ((double)N * (double)(N - 1) * (double)T);
    double r   = mf - (double)target[0];
    out[0] = (float)(r > 0.0 ? r : 0.0);
  }
}

extern "C" void kernel_launch(void* const* d_in, const int* in_sizes, int n_in,
                              void* d_out, int out_size, void* d_ws, size_t ws_size,
                              hipStream_t stream) {
  const float* target = (const float*)d_in[0];
  const float* pred   = (const float*)d_in[1];
  const float* X      = (const float*)d_in[2];
  // d_in[3] = ntimes (==32, hardcoded); d_in[4] = scale
  const float* scale  = (const float*)d_in[4];

  double* partials = (double*)d_ws;  // NTILES doubles, all written every call

  pair_kernel<<<dim3(NTILES), dim3(64), 0, stream>>>(pred, X, scale, partials);
  finalize_kernel<<<dim3(1), dim3(256), 0, stream>>>(partials, target,
                                                     (float*)d_out);
}